// Round 6
// baseline (201.378 us; speedup 1.0000x reference)
//
#include <hip/hip_runtime.h>
#include <math.h>

#define E_N 50
#define D_N 100
#define H_N 100
#define N_ENT 200000
#define NTHR 256
#define GG (E_N * E_N)   // 2500: ints per adj graph; also u32-chunks per gathered bf16 graph

typedef unsigned int u32;
typedef unsigned short u16;
typedef __attribute__((address_space(1))) const void gvoid;
typedef __attribute__((address_space(3))) void lvoid;

__device__ __forceinline__ float bf2f(u32 s16) { return __uint_as_float(s16 << 16); }

__device__ __forceinline__ u16 f2bf(float f) {
    u32 u = __float_as_uint(f);
    return (u16)((u + 0x7FFFu + ((u >> 16) & 1u)) >> 16);  // round-nearest-even
}

template <bool F32>
__device__ __forceinline__ float ldx(const void* p, int i) {
    if (F32) return reinterpret_cast<const float*>(p)[i];
    return bf2f(reinterpret_cast<const u16*>(p)[i]);
}

template <bool F32>
__device__ __forceinline__ float4 ld4(const void* p, long long i4) {
    if (F32) return reinterpret_cast<const float4*>(p)[i4];
    uint2 v = reinterpret_cast<const uint2*>(p)[i4];
    float4 f;
    f.x = bf2f(v.x & 0xFFFFu);
    f.y = bf2f(v.x >> 16);
    f.z = bf2f(v.y & 0xFFFFu);
    f.w = bf2f(v.y >> 16);
    return f;
}

// dtype detector: even halfwords of emb decode sane iff data is bf16
__device__ __forceinline__ int sniff_f32(const void* emb, int tid, int* slot) {
    if (tid < 64) {
        u16 hw = reinterpret_cast<const u16*>(emb)[tid * 2];
        float v = bf2f(hw);
        float a = fabsf(v);
        int sane = (v == 0.f) || (a >= 1e-4f && a <= 8.0f);
        unsigned long long ball = __ballot(sane);
        if (tid == 0) *slot = (__popcll(ball) < 32) ? 1 : 0;
    }
    __syncthreads();
    return *slot;
}

// LDS-visibility barrier WITHOUT draining vmcnt (keeps g1's gathers in flight)
__device__ __forceinline__ void bar_lds() {
    asm volatile("s_waitcnt lgkmcnt(0)" ::: "memory");
    __builtin_amdgcn_sched_barrier(0);
    __builtin_amdgcn_s_barrier();
    __builtin_amdgcn_sched_barrier(0);
}

// ============ prefetch: stream emb table linearly -> populate L3 (MALL) at streaming rate ======
// The harness's 320 MB workspace re-poison evicts L3 every iteration, so the gather's first
// touch of each emb line is otherwise a random 200 B HBM demand-read (~0.75 TB/s measured,
// R0/R2/R4/R5). Linear first-touch runs at ~6.3 TB/s; the gather then hits L3.
__global__ __launch_bounds__(NTHR)
void prefetch_kernel(const void* __restrict__ emb)
{
    __shared__ int is_f32_s;
    int f32 = sniff_f32(emb, threadIdx.x, &is_f32_s);
    size_t bytes = (size_t)N_ENT * D_N * (f32 ? 4 : 2);
    size_t n16 = bytes >> 4;                       // 16B chunks (2.5M bf16 / 5M f32)
    const uint4* p = (const uint4*)emb;
    size_t stride = (size_t)gridDim.x * NTHR;
    u32 a0 = 0, a1 = 0, a2 = 0, a3 = 0;
    for (size_t i = (size_t)blockIdx.x * NTHR + threadIdx.x; i < n16; i += stride) {
        uint4 v = p[i];
        a0 ^= v.x; a1 ^= v.y; a2 ^= v.z; a3 ^= v.w;
    }
    asm volatile("" :: "v"(a0), "v"(a1), "v"(a2), "v"(a3));   // keep loads live (rule #17)
}

// ============ K0: At[dp*100+d] = sum_h Wk[d,h]Wq[dp,h]; c[d] = sum_h Wk[d,h]bq[h] ============
template <bool F32>
__device__ __forceinline__ void precomp_core(
    int dp, int tid, const void* __restrict__ Wq, const void* __restrict__ bq,
    const void* __restrict__ Wk, float* __restrict__ At, float* __restrict__ c,
    float* wq_s, float* bq_s)
{
    if (tid < H_N) wq_s[tid] = ldx<F32>(Wq, dp * H_N + tid);
    if (dp == 0 && tid < H_N) bq_s[tid] = ldx<F32>(bq, tid);
    __syncthreads();
    if (tid < D_N) {
        float a0 = 0.f, a1 = 0.f, a2 = 0.f, a3 = 0.f;
        #pragma unroll
        for (int h4 = 0; h4 < H_N / 4; ++h4) {
            float4 w = ld4<F32>(Wk, (long long)tid * (H_N / 4) + h4);
            a0 = fmaf(w.x, wq_s[h4 * 4 + 0], a0);
            a1 = fmaf(w.y, wq_s[h4 * 4 + 1], a1);
            a2 = fmaf(w.z, wq_s[h4 * 4 + 2], a2);
            a3 = fmaf(w.w, wq_s[h4 * 4 + 3], a3);
        }
        At[dp * D_N + tid] = (a0 + a1) + (a2 + a3);
        if (dp == 0) {
            float c0 = 0.f, c1 = 0.f, c2 = 0.f, c3 = 0.f;
            #pragma unroll
            for (int h4 = 0; h4 < H_N / 4; ++h4) {
                float4 w = ld4<F32>(Wk, (long long)tid * (H_N / 4) + h4);
                c0 = fmaf(w.x, bq_s[h4 * 4 + 0], c0);
                c1 = fmaf(w.y, bq_s[h4 * 4 + 1], c1);
                c2 = fmaf(w.z, bq_s[h4 * 4 + 2], c2);
                c3 = fmaf(w.w, bq_s[h4 * 4 + 3], c3);
            }
            c[tid] = (c0 + c1) + (c2 + c3);
        }
    }
}

__global__ __launch_bounds__(128)
void precomp_kernel(const void* __restrict__ Wq, const void* __restrict__ bq,
                    const void* __restrict__ Wk, const void* __restrict__ emb,
                    float* __restrict__ At, float* __restrict__ c)
{
    __shared__ float wq_s[H_N];
    __shared__ float bq_s[H_N];
    __shared__ int is_f32_s;
    int f32 = sniff_f32(emb, threadIdx.x, &is_f32_s);
    if (f32) precomp_core<true >(blockIdx.x, threadIdx.x, Wq, bq, Wk, At, c, wq_s, bq_s);
    else     precomp_core<false>(blockIdx.x, threadIdx.x, Wq, bq, Wk, At, c, wq_s, bq_s);
}

// ============ per-graph dense pipeline (bf16 path), graph slot q, rows in xq ============
__device__ __forceinline__ void dense_one(
    int q, int gq, int valid, int tid, int mk,
    const float* __restrict__ At, const float* __restrict__ c,
    const void* __restrict__ Wv, const void* __restrict__ bv,
    const void* __restrict__ Ws, const void* __restrict__ bs,
    void* __restrict__ out,
    const u32* xq, float* wls, float* ps, float* ys, float* dens)
{
    // ---- wl[d] = c[d] + sum_dp At[dp,d] * x0[dp] ----
    if (tid < D_N) {
        float acc = c[tid];
        #pragma unroll 4
        for (int dp = 0; dp < D_N; dp += 2) {
            u32 xp = xq[dp >> 1];                             // LDS broadcast
            acc = fmaf(At[dp * D_N + tid],       bf2f(xp & 0xFFFFu), acc);
            acc = fmaf(At[(dp + 1) * D_N + tid], bf2f(xp >> 16),     acc);
        }
        wls[tid] = acc;
    }
    bar_lds();

    // ---- scores + masked softmax on wave q (holds graph q's mask) ----
    if ((tid >> 6) == q) {
        int j = tid & 63;
        float s = 0.f;
        if (j < E_N) {
            const u32* xr = xq + j * 50;
            #pragma unroll 5
            for (int d2 = 0; d2 < 50; ++d2) {
                u32 xp = xr[d2];
                s = fmaf(bf2f(xp & 0xFFFFu), wls[2 * d2],     s);
                s = fmaf(bf2f(xp >> 16),     wls[2 * d2 + 1], s);
            }
            s *= 0.1f;                                        // 1/sqrt(H)
        }
        bool live = (j < E_N) && (mk != 0);
        float m = live ? s : -3.0e38f;
        #pragma unroll
        for (int off = 32; off; off >>= 1)
            m = fmaxf(m, __shfl_xor(m, off));
        float e = live ? __expf(s - m) : 0.f;
        float dn = e;
        #pragma unroll
        for (int off = 32; off; off >>= 1)
            dn += __shfl_xor(dn, off);
        float inv = dn > 0.f ? 1.0f / dn : 0.f;
        if (j < E_N) ps[j] = e * inv;                         // pre-normalized
        if (j == 0)  dens[0] = dn;
    }
    bar_lds();

    // ---- y[d] = sum_j p_j x_j[d]  (lane pairs share LDS word: conflict-free) ----
    if (tid < D_N) {
        const u32* xd = xq + (tid >> 1);
        int hi = tid & 1;
        float acc = 0.f;
        #pragma unroll 10
        for (int j = 0; j < E_N; ++j) {
            u32 xp = xd[j * 50];
            acc = fmaf(ps[j], bf2f(hi ? (xp >> 16) : (xp & 0xFFFFu)), acc);
        }
        ys[tid] = acc;
    }
    bar_lds();

    // ---- out[h] = bs + bv*[den>0] + y.Wv[:,h] + x0.Ws[:,h] ----
    if (tid < H_N && valid) {
        float flag = dens[0] > 0.f ? 1.f : 0.f;
        float acc = ldx<false>(bs, tid) + ldx<false>(bv, tid) * flag;
        #pragma unroll 2
        for (int dp = 0; dp < D_N; dp += 2) {
            u32 xp = xq[dp >> 1];
            acc = fmaf(ys[dp],     ldx<false>(Wv, dp * H_N + tid),       acc);
            acc = fmaf(ys[dp + 1], ldx<false>(Wv, (dp + 1) * H_N + tid), acc);
            acc = fmaf(bf2f(xp & 0xFFFFu), ldx<false>(Ws, dp * H_N + tid),       acc);
            acc = fmaf(bf2f(xp >> 16),     ldx<false>(Ws, (dp + 1) * H_N + tid), acc);
        }
        ((u16*)out)[(size_t)gq * H_N + tid] = f2bf(acc);
    }
}

// ============ fused main (bf16): 2 graphs/block, g0 compute overlaps g1 misses ============
__device__ __forceinline__ void core_bf16(
    int g0, int g1, int valid1, int tid,
    const int* __restrict__ nbr, const int* __restrict__ adj,
    const void* __restrict__ emb,
    const float* __restrict__ At, const float* __restrict__ c,
    const void* __restrict__ Wv, const void* __restrict__ bv,
    const void* __restrict__ Ws, const void* __restrict__ bs,
    void* __restrict__ out,
    u32* xsu, float* wls, float* ps, float* ys, float* dens)
{
    // ---- mask first: wave w holds graph w's row-0 mask (adj symmetric: row0 == col0) ----
    int w = tid >> 6, jj = tid & 63;
    int mk = 0;
    if (w < 2 && jj < E_N)
        mk = adj[(size_t)(w ? g1 : g0) * GG + jj];

    // ---- ALL ids up front (so no later waitcnt drains the gathers) ----
    int idr[20];
    #pragma unroll
    for (int r = 0; r < 10; ++r) {
        int i = tid + NTHR * r;
        idr[r]      = (i < GG) ? nbr[g0 * E_N + i / 50] : 0;
        idr[10 + r] = (i < GG) ? nbr[g1 * E_N + i / 50] : 0;
    }
    asm volatile("" :: "v"(mk));
    __builtin_amdgcn_sched_barrier(0);

    const u16* e16 = (const u16*)emb;
    // ---- g0 gathers (10 wave-instrs) ----
    #pragma unroll
    for (int r = 0; r < 10; ++r) {
        int i = tid + NTHR * r;
        if (i < GG) {
            int cc = i % 50;
            const u16* ga = e16 + (size_t)idr[r] * D_N + cc * 2;
            u32* lb = xsu + (NTHR * r + (tid & ~63));         // wave-uniform base + lane*4
            __builtin_amdgcn_global_load_lds((gvoid*)ga, (lvoid*)lb, 4, 0, 0);
        }
    }
    __builtin_amdgcn_sched_barrier(0);                        // pin g0-before-g1 issue order
    // ---- g1 gathers (stay in flight through g0 compute) ----
    #pragma unroll
    for (int r = 0; r < 10; ++r) {
        int i = tid + NTHR * r;
        if (i < GG) {
            int cc = i % 50;
            const u16* ga = e16 + (size_t)idr[10 + r] * D_N + cc * 2;
            u32* lb = xsu + GG + (NTHR * r + (tid & ~63));
            __builtin_amdgcn_global_load_lds((gvoid*)ga, (lvoid*)lb, 4, 0, 0);
        }
    }
    __builtin_amdgcn_sched_barrier(0);

    // ---- stage 1: wait ONLY g0's 10 oldest; g1's 10 remain outstanding ----
    asm volatile("s_waitcnt vmcnt(10)" ::: "memory");
    __builtin_amdgcn_sched_barrier(0);
    __builtin_amdgcn_s_barrier();
    __builtin_amdgcn_sched_barrier(0);

    dense_one(0, g0, 1, tid, mk, At, c, Wv, bv, Ws, bs, out, xsu, wls, ps, ys, dens);

    // ---- stage 2: full drain (g1 gathers + g0 store) ----
    __syncthreads();
    dense_one(1, g1, valid1, tid, mk, At, c, Wv, bv, Ws, bs, out, xsu + GG, wls, ps, ys, dens);
}

// ---- f32 fallback: one graph at a time (verified in R4/R5) ----
__device__ __forceinline__ void core_f32_one(
    int g, int valid, int tid,
    const int* __restrict__ nbr, const int* __restrict__ adj,
    const void* __restrict__ emb,
    const float* __restrict__ At, const float* __restrict__ c,
    const void* __restrict__ Wv, const void* __restrict__ bv,
    const void* __restrict__ Ws, const void* __restrict__ bs,
    void* __restrict__ out,
    float* xs /*[50][100]*/, float* wls, float* ps, float* ys, float* dens)
{
    int mk = (tid < E_N) ? adj[(size_t)g * GG + tid] : 0;     // symmetric row-0 read
    const float* ef = (const float*)emb;
    {
        int idr[5];
        #pragma unroll
        for (int r = 0; r < 5; ++r) {
            int i = tid + NTHR * r;                           // 16B chunks, 25/row, 1250 total
            idr[r] = (i < E_N * 25) ? nbr[g * E_N + i / 25] : 0;
        }
        #pragma unroll
        for (int r = 0; r < 5; ++r) {
            int i = tid + NTHR * r;
            if (i < E_N * 25) {
                int j = i / 25, d4 = i - j * 25;
                const float* ga = ef + (size_t)idr[r] * D_N + d4 * 4;
                float* lb = xs + 4 * (NTHR * r + (tid & ~63));
                __builtin_amdgcn_global_load_lds((gvoid*)ga, (lvoid*)lb, 16, 0, 0);
            }
        }
    }
    __syncthreads();

    if (tid < D_N) {
        float acc = c[tid];
        #pragma unroll 4
        for (int dp = 0; dp < D_N; ++dp)
            acc = fmaf(At[dp * D_N + tid], xs[dp], acc);      // x0 = xs row 0
        wls[tid] = acc;
    }
    __syncthreads();

    if (tid < 64) {
        float s = 0.f;
        if (tid < E_N) {
            #pragma unroll 10
            for (int d = 0; d < D_N; ++d)
                s = fmaf(wls[d], xs[tid * D_N + d], s);
            s *= 0.1f;
        }
        bool live = (tid < E_N) && (mk != 0);
        float m = live ? s : -3.0e38f;
        #pragma unroll
        for (int off = 32; off; off >>= 1)
            m = fmaxf(m, __shfl_xor(m, off));
        float e = live ? __expf(s - m) : 0.f;
        float dn = e;
        #pragma unroll
        for (int off = 32; off; off >>= 1)
            dn += __shfl_xor(dn, off);
        float inv = dn > 0.f ? 1.0f / dn : 0.f;
        if (tid < E_N) ps[tid] = e * inv;
        if (tid == 0)  dens[0] = dn;
    }
    __syncthreads();

    if (tid < D_N) {
        float acc = 0.f;
        #pragma unroll 10
        for (int j = 0; j < E_N; ++j)
            acc = fmaf(ps[j], xs[j * D_N + tid], acc);
        ys[tid] = acc;
    }
    __syncthreads();

    if (tid < H_N && valid) {
        float flag = dens[0] > 0.f ? 1.f : 0.f;
        float acc = ldx<true>(bs, tid) + ldx<true>(bv, tid) * flag;
        #pragma unroll 4
        for (int d = 0; d < D_N; ++d) {
            acc = fmaf(ys[d], ldx<true>(Wv, d * H_N + tid), acc);
            acc = fmaf(xs[d], ldx<true>(Ws, d * H_N + tid), acc);
        }
        ((float*)out)[(size_t)g * H_N + tid] = acc;
    }
    __syncthreads();   // protect xs before next graph's gather
}

__global__ __launch_bounds__(NTHR, 7)   // LDS ~21 KB -> 7 blocks/CU; cap VGPR so LDS binds
void fused2_kernel(const int* __restrict__ nbr, const int* __restrict__ adj,
                   const void* __restrict__ emb,
                   const float* __restrict__ At, const float* __restrict__ c,
                   const void* __restrict__ Wv, const void* __restrict__ bv,
                   const void* __restrict__ Ws, const void* __restrict__ bs,
                   void* __restrict__ out, int G)
{
    __shared__ __align__(16) u32   xsu[2 * GG];     // 20 KB: bf16 2 graphs / f32 1 graph
    __shared__ __align__(16) float wls[D_N];
    __shared__ __align__(16) float ps [E_N];
    __shared__ __align__(16) float ys [D_N];
    __shared__ float dens[1];
    __shared__ int is_f32_s;

    int tid = threadIdx.x;
    int g0 = blockIdx.x * 2;
    int g1 = (g0 + 1 < G) ? g0 + 1 : G - 1;
    int f32 = sniff_f32(emb, tid, &is_f32_s);

    if (!f32) {
        core_bf16(g0, g1, (g0 + 1 < G) ? 1 : 0, tid, nbr, adj, emb, At, c,
                  Wv, bv, Ws, bs, out, xsu, wls, ps, ys, dens);
    } else {
        float* xsf = reinterpret_cast<float*>(xsu);           // 5000 floats = [50][100]
        core_f32_one(g0, 1, tid, nbr, adj, emb, At, c, Wv, bv, Ws, bs, out,
                     xsf, wls, ps, ys, dens);
        core_f32_one(g1, g0 + 1 < G, tid, nbr, adj, emb, At, c, Wv, bv, Ws, bs, out,
                     xsf, wls, ps, ys, dens);
    }
}

extern "C" void kernel_launch(void* const* d_in, const int* in_sizes, int n_in,
                              void* d_out, int out_size, void* d_ws, size_t ws_size,
                              hipStream_t stream) {
    const int* nbr = (const int*)d_in[0];
    const int* adj = (const int*)d_in[1];
    const void* emb = d_in[2];
    const void* Wq  = d_in[3];
    const void* bq  = d_in[4];
    const void* Wk  = d_in[5];   // d_in[6] = bk cancels inside softmax — unused
    const void* Wv  = d_in[7];
    const void* bv  = d_in[8];
    const void* Ws  = d_in[9];
    const void* bs  = d_in[10];

    const int G = in_sizes[0] / E_N;  // B*L = 3200

    // workspace (f32): At[10000] | c[100]  (40.4 KB)
    float* At = (float*)d_ws;
    float* c  = At + D_N * D_N;

    prefetch_kernel<<<2048, NTHR, 0, stream>>>(emb);          // L3 warm: streaming first-touch
    precomp_kernel<<<D_N, 128, 0, stream>>>(Wq, bq, Wk, emb, At, c);
    fused2_kernel<<<(G + 1) / 2, NTHR, 0, stream>>>(nbr, adj, emb, At, c,
                                                    Wv, bv, Ws, bs, d_out, G);
}

// Round 7
// 186.466 us; speedup vs baseline: 1.0800x; 1.0800x over previous
//
#include <hip/hip_runtime.h>
#include <math.h>

#define E_N 50
#define D_N 100
#define H_N 100
#define NTHR 256
#define GG (E_N * E_N)   // 2500: ints per adj graph; also u32-chunks per gathered bf16 graph

typedef unsigned int u32;
typedef unsigned short u16;
typedef __attribute__((address_space(1))) const void gvoid;
typedef __attribute__((address_space(3))) void lvoid;

__device__ __forceinline__ float bf2f(u32 s16) { return __uint_as_float(s16 << 16); }

__device__ __forceinline__ u16 f2bf(float f) {
    u32 u = __float_as_uint(f);
    return (u16)((u + 0x7FFFu + ((u >> 16) & 1u)) >> 16);  // round-nearest-even
}

template <bool F32>
__device__ __forceinline__ float ldx(const void* p, int i) {
    if (F32) return reinterpret_cast<const float*>(p)[i];
    return bf2f(reinterpret_cast<const u16*>(p)[i]);
}

template <bool F32>
__device__ __forceinline__ float4 ld4(const void* p, long long i4) {
    if (F32) return reinterpret_cast<const float4*>(p)[i4];
    uint2 v = reinterpret_cast<const uint2*>(p)[i4];
    float4 f;
    f.x = bf2f(v.x & 0xFFFFu);
    f.y = bf2f(v.x >> 16);
    f.z = bf2f(v.y & 0xFFFFu);
    f.w = bf2f(v.y >> 16);
    return f;
}

// dtype detector: even halfwords of emb decode sane iff data is bf16
__device__ __forceinline__ int sniff_f32(const void* emb, int tid, int* slot) {
    if (tid < 64) {
        u16 hw = reinterpret_cast<const u16*>(emb)[tid * 2];
        float v = bf2f(hw);
        float a = fabsf(v);
        int sane = (v == 0.f) || (a >= 1e-4f && a <= 8.0f);
        unsigned long long ball = __ballot(sane);
        if (tid == 0) *slot = (__popcll(ball) < 32) ? 1 : 0;
    }
    __syncthreads();
    return *slot;
}

// LDS-visibility barrier WITHOUT draining vmcnt (keeps g1's gathers in flight)
__device__ __forceinline__ void bar_lds() {
    asm volatile("s_waitcnt lgkmcnt(0)" ::: "memory");
    __builtin_amdgcn_sched_barrier(0);
    __builtin_amdgcn_s_barrier();
    __builtin_amdgcn_sched_barrier(0);
}

// ============ K0: At[dp*100+d] = sum_h Wk[d,h]Wq[dp,h]; c[d] = sum_h Wk[d,h]bq[h] ============
template <bool F32>
__device__ __forceinline__ void precomp_core(
    int dp, int tid, const void* __restrict__ Wq, const void* __restrict__ bq,
    const void* __restrict__ Wk, float* __restrict__ At, float* __restrict__ c,
    float* wq_s, float* bq_s)
{
    if (tid < H_N) wq_s[tid] = ldx<F32>(Wq, dp * H_N + tid);
    if (dp == 0 && tid < H_N) bq_s[tid] = ldx<F32>(bq, tid);
    __syncthreads();
    if (tid < D_N) {
        float a0 = 0.f, a1 = 0.f, a2 = 0.f, a3 = 0.f;
        #pragma unroll
        for (int h4 = 0; h4 < H_N / 4; ++h4) {
            float4 w = ld4<F32>(Wk, (long long)tid * (H_N / 4) + h4);
            a0 = fmaf(w.x, wq_s[h4 * 4 + 0], a0);
            a1 = fmaf(w.y, wq_s[h4 * 4 + 1], a1);
            a2 = fmaf(w.z, wq_s[h4 * 4 + 2], a2);
            a3 = fmaf(w.w, wq_s[h4 * 4 + 3], a3);
        }
        At[dp * D_N + tid] = (a0 + a1) + (a2 + a3);
        if (dp == 0) {
            float c0 = 0.f, c1 = 0.f, c2 = 0.f, c3 = 0.f;
            #pragma unroll
            for (int h4 = 0; h4 < H_N / 4; ++h4) {
                float4 w = ld4<F32>(Wk, (long long)tid * (H_N / 4) + h4);
                c0 = fmaf(w.x, bq_s[h4 * 4 + 0], c0);
                c1 = fmaf(w.y, bq_s[h4 * 4 + 1], c1);
                c2 = fmaf(w.z, bq_s[h4 * 4 + 2], c2);
                c3 = fmaf(w.w, bq_s[h4 * 4 + 3], c3);
            }
            c[tid] = (c0 + c1) + (c2 + c3);
        }
    }
}

__global__ __launch_bounds__(128)
void precomp_kernel(const void* __restrict__ Wq, const void* __restrict__ bq,
                    const void* __restrict__ Wk, const void* __restrict__ emb,
                    float* __restrict__ At, float* __restrict__ c)
{
    __shared__ float wq_s[H_N];
    __shared__ float bq_s[H_N];
    __shared__ int is_f32_s;
    int f32 = sniff_f32(emb, threadIdx.x, &is_f32_s);
    if (f32) precomp_core<true >(blockIdx.x, threadIdx.x, Wq, bq, Wk, At, c, wq_s, bq_s);
    else     precomp_core<false>(blockIdx.x, threadIdx.x, Wq, bq, Wk, At, c, wq_s, bq_s);
}

// ============ per-graph dense pipeline (bf16 path), graph slot q, rows in xq ============
// wl = A x0 + c; s_j = 0.1 x_j.wl; masked softmax (wave q) -> ps; y = sum p x;
// out = bs + bv*[den>0] + y.Wv + x0.Ws
__device__ __forceinline__ void dense_one(
    int q, int gq, int valid, int tid, int mk,
    const float* __restrict__ At, const float* __restrict__ c,
    const void* __restrict__ Wv, const void* __restrict__ bv,
    const void* __restrict__ Ws, const void* __restrict__ bs,
    void* __restrict__ out,
    const u32* xq, float* wls, float* ps, float* ys, float* dens)
{
    // ---- wl[d] = c[d] + sum_dp At[dp,d] * x0[dp] ----
    if (tid < D_N) {
        float acc = c[tid];
        #pragma unroll 4
        for (int dp = 0; dp < D_N; dp += 2) {
            u32 xp = xq[dp >> 1];                             // LDS broadcast
            acc = fmaf(At[dp * D_N + tid],       bf2f(xp & 0xFFFFu), acc);
            acc = fmaf(At[(dp + 1) * D_N + tid], bf2f(xp >> 16),     acc);
        }
        wls[tid] = acc;
    }
    bar_lds();

    // ---- scores + masked softmax on wave q (holds graph q's mask) ----
    if ((tid >> 6) == q) {
        int j = tid & 63;
        float s = 0.f;
        if (j < E_N) {
            const u32* xr = xq + j * 50;
            #pragma unroll 5
            for (int d2 = 0; d2 < 50; ++d2) {
                u32 xp = xr[d2];
                s = fmaf(bf2f(xp & 0xFFFFu), wls[2 * d2],     s);
                s = fmaf(bf2f(xp >> 16),     wls[2 * d2 + 1], s);
            }
            s *= 0.1f;                                        // 1/sqrt(H)
        }
        bool live = (j < E_N) && (mk != 0);
        float m = live ? s : -3.0e38f;
        #pragma unroll
        for (int off = 32; off; off >>= 1)
            m = fmaxf(m, __shfl_xor(m, off));
        float e = live ? __expf(s - m) : 0.f;
        float dn = e;
        #pragma unroll
        for (int off = 32; off; off >>= 1)
            dn += __shfl_xor(dn, off);
        float inv = dn > 0.f ? 1.0f / dn : 0.f;
        if (j < E_N) ps[j] = e * inv;                         // pre-normalized
        if (j == 0)  dens[0] = dn;
    }
    bar_lds();

    // ---- y[d] = sum_j p_j x_j[d]  (lane pairs share LDS word: conflict-free) ----
    if (tid < D_N) {
        const u32* xd = xq + (tid >> 1);
        int hi = tid & 1;
        float acc = 0.f;
        #pragma unroll 10
        for (int j = 0; j < E_N; ++j) {
            u32 xp = xd[j * 50];
            acc = fmaf(ps[j], bf2f(hi ? (xp >> 16) : (xp & 0xFFFFu)), acc);
        }
        ys[tid] = acc;
    }
    bar_lds();

    // ---- out[h] = bs + bv*[den>0] + y.Wv[:,h] + x0.Ws[:,h] ----
    if (tid < H_N && valid) {
        float flag = dens[0] > 0.f ? 1.f : 0.f;
        float acc = ldx<false>(bs, tid) + ldx<false>(bv, tid) * flag;
        #pragma unroll 2
        for (int dp = 0; dp < D_N; dp += 2) {
            u32 xp = xq[dp >> 1];
            acc = fmaf(ys[dp],     ldx<false>(Wv, dp * H_N + tid),       acc);
            acc = fmaf(ys[dp + 1], ldx<false>(Wv, (dp + 1) * H_N + tid), acc);
            acc = fmaf(bf2f(xp & 0xFFFFu), ldx<false>(Ws, dp * H_N + tid),       acc);
            acc = fmaf(bf2f(xp >> 16),     ldx<false>(Ws, (dp + 1) * H_N + tid), acc);
        }
        ((u16*)out)[(size_t)gq * H_N + tid] = f2bf(acc);
    }
}

// ============ fused main (bf16): 2 graphs/block, g0 compute overlaps g1 misses ============
__device__ __forceinline__ void core_bf16(
    int g0, int g1, int valid1, int tid,
    const int* __restrict__ nbr, const int* __restrict__ adj,
    const void* __restrict__ emb,
    const float* __restrict__ At, const float* __restrict__ c,
    const void* __restrict__ Wv, const void* __restrict__ bv,
    const void* __restrict__ Ws, const void* __restrict__ bs,
    void* __restrict__ out,
    u32* xsu, float* wls, float* ps, float* ys, float* dens)
{
    // ---- mask first: wave w holds graph w's row-0 mask (adj symmetric: row0 == col0) ----
    int w = tid >> 6, jj = tid & 63;
    int mk = 0;
    if (w < 2 && jj < E_N)
        mk = adj[(size_t)(w ? g1 : g0) * GG + jj];

    // ---- ALL ids up front (so no later waitcnt drains the gathers) ----
    int idr[20];
    #pragma unroll
    for (int r = 0; r < 10; ++r) {
        int i = tid + NTHR * r;
        idr[r]      = (i < GG) ? nbr[g0 * E_N + i / 50] : 0;
        idr[10 + r] = (i < GG) ? nbr[g1 * E_N + i / 50] : 0;
    }
    asm volatile("" :: "v"(mk));   // force mk consumed -> its load retires before gathers
    __builtin_amdgcn_sched_barrier(0);

    const u16* e16 = (const u16*)emb;
    // ---- g0 gathers (10 wave-instrs) ----
    #pragma unroll
    for (int r = 0; r < 10; ++r) {
        int i = tid + NTHR * r;
        if (i < GG) {
            int cc = i % 50;
            const u16* ga = e16 + (size_t)idr[r] * D_N + cc * 2;
            u32* lb = xsu + (NTHR * r + (tid & ~63));         // wave-uniform base + lane*4
            __builtin_amdgcn_global_load_lds((gvoid*)ga, (lvoid*)lb, 4, 0, 0);
        }
    }
    __builtin_amdgcn_sched_barrier(0);                        // pin g0-before-g1 issue order
    // ---- g1 gathers (stay in flight through g0 compute) ----
    #pragma unroll
    for (int r = 0; r < 10; ++r) {
        int i = tid + NTHR * r;
        if (i < GG) {
            int cc = i % 50;
            const u16* ga = e16 + (size_t)idr[10 + r] * D_N + cc * 2;
            u32* lb = xsu + GG + (NTHR * r + (tid & ~63));
            __builtin_amdgcn_global_load_lds((gvoid*)ga, (lvoid*)lb, 4, 0, 0);
        }
    }
    __builtin_amdgcn_sched_barrier(0);

    // ---- stage 1: wait ONLY g0's 10 oldest; g1's 10 remain outstanding ----
    asm volatile("s_waitcnt vmcnt(10)" ::: "memory");
    __builtin_amdgcn_sched_barrier(0);
    __builtin_amdgcn_s_barrier();
    __builtin_amdgcn_sched_barrier(0);

    dense_one(0, g0, 1, tid, mk, At, c, Wv, bv, Ws, bs, out, xsu, wls, ps, ys, dens);

    // ---- stage 2: full drain (g1 gathers + g0 store) ----
    __syncthreads();
    dense_one(1, g1, valid1, tid, mk, At, c, Wv, bv, Ws, bs, out, xsu + GG, wls, ps, ys, dens);
}

// ---- f32 fallback: one graph at a time (verified in R4/R5) ----
__device__ __forceinline__ void core_f32_one(
    int g, int valid, int tid,
    const int* __restrict__ nbr, const int* __restrict__ adj,
    const void* __restrict__ emb,
    const float* __restrict__ At, const float* __restrict__ c,
    const void* __restrict__ Wv, const void* __restrict__ bv,
    const void* __restrict__ Ws, const void* __restrict__ bs,
    void* __restrict__ out,
    float* xs /*[50][100]*/, float* wls, float* ps, float* ys, float* dens)
{
    int mk = (tid < E_N) ? adj[(size_t)g * GG + tid] : 0;     // symmetric row-0 read
    const float* ef = (const float*)emb;
    {
        int idr[5];
        #pragma unroll
        for (int r = 0; r < 5; ++r) {
            int i = tid + NTHR * r;                           // 16B chunks, 25/row, 1250 total
            idr[r] = (i < E_N * 25) ? nbr[g * E_N + i / 25] : 0;
        }
        #pragma unroll
        for (int r = 0; r < 5; ++r) {
            int i = tid + NTHR * r;
            if (i < E_N * 25) {
                int j = i / 25, d4 = i - j * 25;
                const float* ga = ef + (size_t)idr[r] * D_N + d4 * 4;
                float* lb = xs + 4 * (NTHR * r + (tid & ~63));
                __builtin_amdgcn_global_load_lds((gvoid*)ga, (lvoid*)lb, 16, 0, 0);
            }
        }
    }
    __syncthreads();

    if (tid < D_N) {
        float acc = c[tid];
        #pragma unroll 4
        for (int dp = 0; dp < D_N; ++dp)
            acc = fmaf(At[dp * D_N + tid], xs[dp], acc);      // x0 = xs row 0
        wls[tid] = acc;
    }
    __syncthreads();

    if (tid < 64) {
        float s = 0.f;
        if (tid < E_N) {
            #pragma unroll 10
            for (int d = 0; d < D_N; ++d)
                s = fmaf(wls[d], xs[tid * D_N + d], s);
            s *= 0.1f;
        }
        bool live = (tid < E_N) && (mk != 0);
        float m = live ? s : -3.0e38f;
        #pragma unroll
        for (int off = 32; off; off >>= 1)
            m = fmaxf(m, __shfl_xor(m, off));
        float e = live ? __expf(s - m) : 0.f;
        float dn = e;
        #pragma unroll
        for (int off = 32; off; off >>= 1)
            dn += __shfl_xor(dn, off);
        float inv = dn > 0.f ? 1.0f / dn : 0.f;
        if (tid < E_N) ps[tid] = e * inv;
        if (tid == 0)  dens[0] = dn;
    }
    __syncthreads();

    if (tid < D_N) {
        float acc = 0.f;
        #pragma unroll 10
        for (int j = 0; j < E_N; ++j)
            acc = fmaf(ps[j], xs[j * D_N + tid], acc);
        ys[tid] = acc;
    }
    __syncthreads();

    if (tid < H_N && valid) {
        float flag = dens[0] > 0.f ? 1.f : 0.f;
        float acc = ldx<true>(bs, tid) + ldx<true>(bv, tid) * flag;
        #pragma unroll 4
        for (int d = 0; d < D_N; ++d) {
            acc = fmaf(ys[d], ldx<true>(Wv, d * H_N + tid), acc);
            acc = fmaf(xs[d], ldx<true>(Ws, d * H_N + tid), acc);
        }
        ((float*)out)[(size_t)g * H_N + tid] = acc;
    }
    __syncthreads();   // protect xs before next graph's gather
}

__global__ __launch_bounds__(NTHR, 7)   // LDS ~21 KB -> 7 blocks/CU; cap VGPR so LDS binds
void fused2_kernel(const int* __restrict__ nbr, const int* __restrict__ adj,
                   const void* __restrict__ emb,
                   const float* __restrict__ At, const float* __restrict__ c,
                   const void* __restrict__ Wv, const void* __restrict__ bv,
                   const void* __restrict__ Ws, const void* __restrict__ bs,
                   void* __restrict__ out, int G)
{
    __shared__ __align__(16) u32   xsu[2 * GG];     // 20 KB: bf16 2 graphs / f32 1 graph
    __shared__ __align__(16) float wls[D_N];
    __shared__ __align__(16) float ps [E_N];
    __shared__ __align__(16) float ys [D_N];
    __shared__ float dens[1];
    __shared__ int is_f32_s;

    int tid = threadIdx.x;
    int g0 = blockIdx.x * 2;
    int g1 = (g0 + 1 < G) ? g0 + 1 : G - 1;
    int f32 = sniff_f32(emb, tid, &is_f32_s);

    if (!f32) {
        core_bf16(g0, g1, (g0 + 1 < G) ? 1 : 0, tid, nbr, adj, emb, At, c,
                  Wv, bv, Ws, bs, out, xsu, wls, ps, ys, dens);
    } else {
        float* xsf = reinterpret_cast<float*>(xsu);           // 5000 floats = [50][100]
        core_f32_one(g0, 1, tid, nbr, adj, emb, At, c, Wv, bv, Ws, bs, out,
                     xsf, wls, ps, ys, dens);
        core_f32_one(g1, g0 + 1 < G, tid, nbr, adj, emb, At, c, Wv, bv, Ws, bs, out,
                     xsf, wls, ps, ys, dens);
    }
}

extern "C" void kernel_launch(void* const* d_in, const int* in_sizes, int n_in,
                              void* d_out, int out_size, void* d_ws, size_t ws_size,
                              hipStream_t stream) {
    const int* nbr = (const int*)d_in[0];
    const int* adj = (const int*)d_in[1];
    const void* emb = d_in[2];
    const void* Wq  = d_in[3];
    const void* bq  = d_in[4];
    const void* Wk  = d_in[5];   // d_in[6] = bk cancels inside softmax — unused
    const void* Wv  = d_in[7];
    const void* bv  = d_in[8];
    const void* Ws  = d_in[9];
    const void* bs  = d_in[10];

    const int G = in_sizes[0] / E_N;  // B*L = 3200

    // workspace (f32): At[10000] | c[100]  (40.4 KB)
    float* At = (float*)d_ws;
    float* c  = At + D_N * D_N;

    precomp_kernel<<<D_N, 128, 0, stream>>>(Wq, bq, Wk, emb, At, c);
    fused2_kernel<<<(G + 1) / 2, NTHR, 0, stream>>>(nbr, adj, emb, At, c,
                                                    Wv, bv, Ws, bs, d_out, G);
}